// Round 4
// baseline (38.185 us; speedup 1.0000x reference)
//
#include <hip/hip_runtime.h>

typedef unsigned short ushort_t;
using f32x4  = __attribute__((ext_vector_type(4))) float;
using bf16x8 = __attribute__((ext_vector_type(8))) short;
using u16x8  = __attribute__((ext_vector_type(8))) unsigned short;

constexpr int Bc = 4;
constexpr int Nc = 512;
constexpr int Dc = 512;
constexpr int Pc = 128;
constexpr int ROWS = Bc * Nc;   // 2048

__device__ inline unsigned short f2bf(float f) {
    unsigned u = __builtin_bit_cast(unsigned, f);
    unsigned r = u + 0x7fffu + ((u >> 16) & 1u);   // RNE
    return (unsigned short)(r >> 16);
}

__device__ inline void gload_lds16(const void* g, void* l) {
    __builtin_amdgcn_global_load_lds(
        (const __attribute__((address_space(1))) unsigned int*)g,
        (__attribute__((address_space(3))) unsigned int*)l, 16, 0, 0);
}

// ---------------------------------------------------------------------------
// convert: produce MFMA-fragment-ordered bf16 tensors.
//   inBF2 [mt(32)][ks(8)][kc(8)][row(64)][8]  : element = input[64mt+row][64ks+8kc+i]
//   WcatT2[nt(8)][ks(8)][kc(8)][col(64)][8]   : element = Wcat[64ks+8kc+i][64nt+col]
// blocks 0..255: A-part (mt = bx>>3, ks = bx&7). blocks 256..319: W-part.
// ---------------------------------------------------------------------------
__global__ __launch_bounds__(256) void convert_kernel(
    const float* __restrict__ input,
    const float* __restrict__ Wl,  const float* __restrict__ Wr,
    const float* __restrict__ Ws1, const float* __restrict__ We1,
    ushort_t* __restrict__ inBF2, ushort_t* __restrict__ WcatT2)
{
    const int bx = blockIdx.x, t = threadIdx.x;
    __shared__ float T[64][68];

    if (bx < 256) {
        const int mt = bx >> 3, ks = bx & 7;
        const int c = t & 7, r0 = t >> 3;           // c: k-chunk, r0: 0..31
        const float* src = input + (size_t)(mt * 64) * Dc + ks * 64;
        ushort_t* dstc = inBF2 + ((size_t)(mt * 8 + ks) * 8 + c) * 512;
        #pragma unroll
        for (int h = 0; h < 2; ++h) {
            const int r = r0 + h * 32;
            const float* s = src + (size_t)r * Dc + c * 8;
            float4 v0 = *(const float4*)s;
            float4 v1 = *(const float4*)(s + 4);
            u16x8 o;
            o[0] = f2bf(v0.x); o[1] = f2bf(v0.y); o[2] = f2bf(v0.z); o[3] = f2bf(v0.w);
            o[4] = f2bf(v1.x); o[5] = f2bf(v1.y); o[6] = f2bf(v1.z); o[7] = f2bf(v1.w);
            *(u16x8*)(dstc + r * 8) = o;
        }
    } else {
        const int idx = bx - 256;
        const int nt = idx >> 3, ks = idx & 7;
        const int mi = nt >> 1, cm0 = (nt & 1) * 64;
        const float* Wm = (mi == 0) ? Wl : (mi == 1) ? Wr : (mi == 2) ? Ws1 : We1;

        const int kk_ = t >> 4, cc = (t & 15) << 2;
        #pragma unroll
        for (int u = 0; u < 4; ++u)
            *(float4*)&T[kk_ + 16 * u][cc] =
                *(const float4*)&Wm[(size_t)(ks * 64 + kk_ + 16 * u) * Pc + cm0 + cc];
        __syncthreads();

        const int col = t & 63, c2 = t >> 6;
        #pragma unroll
        for (int h = 0; h < 2; ++h) {
            const int kc = c2 + h * 4;
            u16x8 o;
            #pragma unroll
            for (int i = 0; i < 8; ++i) o[i] = f2bf(T[kc * 8 + i][col]);
            *(u16x8*)(WcatT2 + ((size_t)(nt * 8 + ks) * 8 + kc) * 512 + col * 8) = o;
        }
    }
}

// ---------------------------------------------------------------------------
// mfma_proj2: C[2048,512] = inBF @ Wcat via mfma_f32_16x16x32_bf16.
// grid (32 mt, 8 ny), 256 thr = 4 waves (2M x 2N quadrants of 32x32).
// Double-buffered LDS, staged with global_load_lds width-16 (linear dest,
// fragment-ordered source). One barrier per K-step.
// ny 0..3 -> left/right; ny 4..7 -> start/end partial dots -> parts.
// ---------------------------------------------------------------------------
__global__ __launch_bounds__(256) void mfma_proj2(
    const ushort_t* __restrict__ inBF2, const ushort_t* __restrict__ WcatT2,
    const float* __restrict__ bl,
    const float* __restrict__ bs1, const float* __restrict__ Ws2,
    const float* __restrict__ be1, const float* __restrict__ We2,
    float* __restrict__ left, float* __restrict__ right,
    float* __restrict__ parts)
{
    const int mt = blockIdx.x, ny = blockIdx.y;
    const int row0 = mt * 64;
    const int t = threadIdx.x, w = t >> 6, l = t & 63;
    const int wm = w >> 1, wn = w & 1;
    const int fr = l & 15, fg = l >> 4;

    __shared__ ushort_t As2[2][4096];
    __shared__ ushort_t Bs2[2][4096];
    __shared__ float red[2][64];

    const ushort_t* Abase = inBF2  + (size_t)mt * 8 * 4096;
    const ushort_t* Bbase = WcatT2 + (size_t)ny * 8 * 4096;

    f32x4 acc[2][2];
    #pragma unroll
    for (int m = 0; m < 2; ++m)
        #pragma unroll
        for (int n = 0; n < 2; ++n)
            acc[m][n] = f32x4{0.f, 0.f, 0.f, 0.f};

    const int c0 = 2 * w, c1 = 2 * w + 1;   // this wave's two 1KB chunks

#define STAGE(BI, KS)                                                        \
    {                                                                        \
        const ushort_t* ga = Abase + (KS) * 4096;                            \
        const ushort_t* gb = Bbase + (KS) * 4096;                            \
        gload_lds16(ga + c0 * 512 + l * 8, &As2[BI][c0 * 512]);              \
        gload_lds16(ga + c1 * 512 + l * 8, &As2[BI][c1 * 512]);              \
        gload_lds16(gb + c0 * 512 + l * 8, &Bs2[BI][c0 * 512]);              \
        gload_lds16(gb + c1 * 512 + l * 8, &Bs2[BI][c1 * 512]);              \
    }

    STAGE(0, 0);
    __syncthreads();

    for (int ks = 0; ks < 8; ++ks) {
        const int bi = ks & 1;
        if (ks < 7) STAGE(bi ^ 1, ks + 1);
        #pragma unroll
        for (int kk = 0; kk < 2; ++kk) {
            const int kc = kk * 4 + fg;
            bf16x8 a0 = *(const bf16x8*)&As2[bi][(kc * 64 + wm * 32 + fr) * 8];
            bf16x8 a1 = *(const bf16x8*)&As2[bi][(kc * 64 + wm * 32 + 16 + fr) * 8];
            bf16x8 b0 = *(const bf16x8*)&Bs2[bi][(kc * 64 + wn * 32 + fr) * 8];
            bf16x8 b1 = *(const bf16x8*)&Bs2[bi][(kc * 64 + wn * 32 + 16 + fr) * 8];
            acc[0][0] = __builtin_amdgcn_mfma_f32_16x16x32_bf16(a0, b0, acc[0][0], 0, 0, 0);
            acc[0][1] = __builtin_amdgcn_mfma_f32_16x16x32_bf16(a0, b1, acc[0][1], 0, 0, 0);
            acc[1][0] = __builtin_amdgcn_mfma_f32_16x16x32_bf16(a1, b0, acc[1][0], 0, 0, 0);
            acc[1][1] = __builtin_amdgcn_mfma_f32_16x16x32_bf16(a1, b1, acc[1][1], 0, 0, 0);
        }
        __syncthreads();
    }
#undef STAGE

    const int fq4 = fg << 2;    // D row base = (lane>>4)*4
    if (ny < 4) {
        float* outp = (ny < 2) ? left : right;
        const int cbase = (ny & 1) * 64 + wn * 32;
        #pragma unroll
        for (int m = 0; m < 2; ++m) {
            const int row = row0 + wm * 32 + m * 16 + fq4;
            #pragma unroll
            for (int n = 0; n < 2; ++n) {
                const int col = cbase + n * 16 + fr;
                const float bv = (ny < 2) ? bl[col] : 0.f;
                #pragma unroll
                for (int q = 0; q < 4; ++q)
                    outp[(size_t)(row + q) * Pc + col] = acc[m][n][q] + bv;
            }
        }
    } else {
        const float* b1 = (ny < 6) ? bs1 : be1;
        const float* W2 = (ny < 6) ? Ws2 : We2;
        const int pbase = (ny < 6) ? (ny - 4) * 64 : (ny - 6) * 64;
        float vs[2][4];
        #pragma unroll
        for (int m = 0; m < 2; ++m)
            #pragma unroll
            for (int q = 0; q < 4; ++q) {
                float v = 0.f;
                #pragma unroll
                for (int n = 0; n < 2; ++n) {
                    const int cp = pbase + wn * 32 + n * 16 + fr;
                    v += fmaxf(acc[m][n][q] + b1[cp], 0.f) * W2[cp];
                }
                v += __shfl_xor(v, 1);
                v += __shfl_xor(v, 2);
                v += __shfl_xor(v, 4);
                v += __shfl_xor(v, 8);
                vs[m][q] = v;
            }
        if (fr == 0) {
            #pragma unroll
            for (int m = 0; m < 2; ++m)
                #pragma unroll
                for (int q = 0; q < 4; ++q)
                    red[wn][wm * 32 + m * 16 + fq4 + q] = vs[m][q];
        }
        __syncthreads();
        if (t < 64) {
            const int pi = ny - 4;
            parts[pi * ROWS + row0 + t] = red[0][t] + red[1][t];
        }
    }
}

// ---------------------------------------------------------------------------
// bigram (unchanged control): 32i x 64j tiles, thread = 2i x 4j, ping-pong.
// jt==8 blocks combine start/end partials.
// ---------------------------------------------------------------------------
__global__ __launch_bounds__(256) void bigram_kernel(
    const float* __restrict__ left, const float* __restrict__ right,
    const float* __restrict__ Wo,   const float* __restrict__ bo,
    const float* __restrict__ parts,
    const float* __restrict__ bs2,  const float* __restrict__ be2,
    float* __restrict__ out, float* __restrict__ start_out,
    float* __restrict__ end_out)
{
    const int jt = blockIdx.x, it = blockIdx.y, b = blockIdx.z;
    const int t  = threadIdx.x;

    if (jt == 8) {
        if (it >= 8) return;
        const int base = (b * 8 + it) * 64;
        if (t < 64) {
            const int r = base + t;
            start_out[r] = parts[r] + parts[ROWS + r] + bs2[0];
        } else if (t < 128) {
            const int r = base + t - 64;
            end_out[r] = parts[2 * ROWS + r] + parts[3 * ROWS + r] + be2[0];
        }
        return;
    }

    __shared__ float Ls[64][132];
    __shared__ float Rs[32][132];
    __shared__ float wos[Pc];

    const float* lp = left  + (size_t)(b * Nc + jt * 64) * Pc;
    const float* rp = right + (size_t)(b * Nc + it * 32) * Pc;

    #pragma unroll
    for (int u = 0; u < 8; ++u) {
        int f = t + u * 256, r = f >> 5, p4 = (f & 31) << 2;
        *(float4*)&Ls[r][p4] = *(const float4*)&lp[r * Pc + p4];
    }
    #pragma unroll
    for (int u = 0; u < 4; ++u) {
        int f = t + u * 256, r = f >> 5, p4 = (f & 31) << 2;
        *(float4*)&Rs[r][p4] = *(const float4*)&rp[r * Pc + p4];
    }
    if (t < 32) *(float4*)&wos[t << 2] = *(const float4*)&Wo[t << 2];
    __syncthreads();

    const int jl = t & 15;
    const int il = t >> 4;

    float acc[2][4] = {};

#define LOADG(P, W4, L4, R4)                                             \
    {                                                                    \
        W4 = *(const float4*)&wos[(P)];                                  \
        _Pragma("unroll") for (int jj = 0; jj < 4; ++jj)                 \
            L4[jj] = *(const float4*)&Ls[jl + 16 * jj][(P)];             \
        _Pragma("unroll") for (int ii = 0; ii < 2; ++ii)                 \
            R4[ii] = *(const float4*)&Rs[il + 16 * ii][(P)];             \
    }

#define COMPUTE(W4, L4, R4)                                              \
    {                                                                    \
        _Pragma("unroll") for (int ii = 0; ii < 2; ++ii)                 \
        _Pragma("unroll") for (int jj = 0; jj < 4; ++jj) {               \
            acc[ii][jj] = fmaf(fmaxf(L4[jj].x + R4[ii].x, 0.f), W4.x, acc[ii][jj]); \
            acc[ii][jj] = fmaf(fmaxf(L4[jj].y + R4[ii].y, 0.f), W4.y, acc[ii][jj]); \
            acc[ii][jj] = fmaf(fmaxf(L4[jj].z + R4[ii].z, 0.f), W4.z, acc[ii][jj]); \
            acc[ii][jj] = fmaf(fmaxf(L4[jj].w + R4[ii].w, 0.f), W4.w, acc[ii][jj]); \
        }                                                                \
    }

    float4 wa, la[4], ra[2];
    float4 wb, lb4[4], rb4[2];
    LOADG(0, wa, la, ra);

    #pragma unroll 1
    for (int p = 0; p < Pc; p += 8) {
        LOADG(p + 4, wb, lb4, rb4);
        COMPUTE(wa, la, ra);
        if (p + 8 < Pc) LOADG(p + 8, wa, la, ra);
        COMPUTE(wb, lb4, rb4);
    }

    const float bias = bo[0];
    #pragma unroll
    for (int ii = 0; ii < 2; ++ii) {
        #pragma unroll
        for (int jj = 0; jj < 4; ++jj) {
            const int gi = it * 32 + il + 16 * ii;
            const int gj = jt * 64 + jl + 16 * jj;
            out[((size_t)b * Nc + gi) * Nc + gj] = acc[ii][jj] + bias;
        }
    }
#undef LOADG
#undef COMPUTE
}

extern "C" void kernel_launch(void* const* d_in, const int* in_sizes, int n_in,
                              void* d_out, int out_size, void* d_ws, size_t ws_size,
                              hipStream_t stream) {
    const float* input = (const float*)d_in[0];
    const float* Wl  = (const float*)d_in[1];
    const float* bl  = (const float*)d_in[2];
    const float* Wr  = (const float*)d_in[3];
    const float* Wo  = (const float*)d_in[4];
    const float* bo  = (const float*)d_in[5];
    const float* Ws1 = (const float*)d_in[6];
    const float* bs1 = (const float*)d_in[7];
    const float* Ws2 = (const float*)d_in[8];
    const float* bs2 = (const float*)d_in[9];
    const float* We1 = (const float*)d_in[10];
    const float* be1 = (const float*)d_in[11];
    const float* We2 = (const float*)d_in[12];
    const float* be2 = (const float*)d_in[13];

    float* out    = (float*)d_out;
    float* bigram = out;
    float* start  = out + (size_t)Bc * Nc * Nc;
    float* end    = start + (size_t)Bc * Nc;

    float* left   = (float*)d_ws;                       // 2048*128 f
    float* right  = left + (size_t)ROWS * Pc;           // 2048*128 f
    float* parts  = right + (size_t)ROWS * Pc;          // 4*2048 f
    ushort_t* inBF2  = (ushort_t*)(parts + 4 * ROWS);   // 2048*512 bf16 (tiled)
    ushort_t* WcatT2 = inBF2 + (size_t)ROWS * Dc;       // 512*512 bf16 (tiled)

    convert_kernel<<<320, 256, 0, stream>>>(input, Wl, Wr, Ws1, We1, inBF2, WcatT2);

    mfma_proj2<<<dim3(32, 8), 256, 0, stream>>>(
        inBF2, WcatT2, bl, bs1, Ws2, be1, We2, left, right, parts);

    bigram_kernel<<<dim3(9, 16, 4), 256, 0, stream>>>(
        left, right, Wo, bo, parts, bs2, be2, bigram, start, end);
}

// Round 5
// 31.524 us; speedup vs baseline: 1.2113x; 1.2113x over previous
//
#include <hip/hip_runtime.h>

typedef unsigned short ushort_t;
using f32x4  = __attribute__((ext_vector_type(4))) float;
using bf16x8 = __attribute__((ext_vector_type(8))) short;
using u16x8  = __attribute__((ext_vector_type(8))) unsigned short;
using h2v    = __attribute__((ext_vector_type(2))) _Float16;

constexpr int Bc = 4;
constexpr int Nc = 512;
constexpr int Dc = 512;
constexpr int Pc = 128;
constexpr int ROWS = Bc * Nc;   // 2048

__device__ inline unsigned short f2bf(float f) {
    unsigned u = __builtin_bit_cast(unsigned, f);
    unsigned r = u + 0x7fffu + ((u >> 16) & 1u);   // RNE
    return (unsigned short)(r >> 16);
}

__device__ inline void gload_lds16(const void* g, void* l) {
    __builtin_amdgcn_global_load_lds(
        (const __attribute__((address_space(1))) unsigned int*)g,
        (__attribute__((address_space(3))) unsigned int*)l, 16, 0, 0);
}

__device__ inline unsigned packh2(float a, float b) {
    unsigned short lo = __builtin_bit_cast(unsigned short, (_Float16)a);
    unsigned short hi = __builtin_bit_cast(unsigned short, (_Float16)b);
    return (unsigned)lo | ((unsigned)hi << 16);
}

// ---------------------------------------------------------------------------
// convert (unchanged from round 4): MFMA-fragment-ordered bf16 tensors.
// ---------------------------------------------------------------------------
__global__ __launch_bounds__(256) void convert_kernel(
    const float* __restrict__ input,
    const float* __restrict__ Wl,  const float* __restrict__ Wr,
    const float* __restrict__ Ws1, const float* __restrict__ We1,
    ushort_t* __restrict__ inBF2, ushort_t* __restrict__ WcatT2)
{
    const int bx = blockIdx.x, t = threadIdx.x;
    __shared__ float T[64][68];

    if (bx < 256) {
        const int mt = bx >> 3, ks = bx & 7;
        const int c = t & 7, r0 = t >> 3;
        const float* src = input + (size_t)(mt * 64) * Dc + ks * 64;
        ushort_t* dstc = inBF2 + ((size_t)(mt * 8 + ks) * 8 + c) * 512;
        #pragma unroll
        for (int h = 0; h < 2; ++h) {
            const int r = r0 + h * 32;
            const float* s = src + (size_t)r * Dc + c * 8;
            float4 v0 = *(const float4*)s;
            float4 v1 = *(const float4*)(s + 4);
            u16x8 o;
            o[0] = f2bf(v0.x); o[1] = f2bf(v0.y); o[2] = f2bf(v0.z); o[3] = f2bf(v0.w);
            o[4] = f2bf(v1.x); o[5] = f2bf(v1.y); o[6] = f2bf(v1.z); o[7] = f2bf(v1.w);
            *(u16x8*)(dstc + r * 8) = o;
        }
    } else {
        const int idx = bx - 256;
        const int nt = idx >> 3, ks = idx & 7;
        const int mi = nt >> 1, cm0 = (nt & 1) * 64;
        const float* Wm = (mi == 0) ? Wl : (mi == 1) ? Wr : (mi == 2) ? Ws1 : We1;

        const int kk_ = t >> 4, cc = (t & 15) << 2;
        #pragma unroll
        for (int u = 0; u < 4; ++u)
            *(float4*)&T[kk_ + 16 * u][cc] =
                *(const float4*)&Wm[(size_t)(ks * 64 + kk_ + 16 * u) * Pc + cm0 + cc];
        __syncthreads();

        const int col = t & 63, c2 = t >> 6;
        #pragma unroll
        for (int h = 0; h < 2; ++h) {
            const int kc = c2 + h * 4;
            u16x8 o;
            #pragma unroll
            for (int i = 0; i < 8; ++i) o[i] = f2bf(T[kc * 8 + i][col]);
            *(u16x8*)(WcatT2 + ((size_t)(nt * 8 + ks) * 8 + kc) * 512 + col * 8) = o;
        }
    }
}

// ---------------------------------------------------------------------------
// mfma_proj2 (round-4 structure); epilogue now stores left/right as packed
// f16 rows [2048][128] ushort for the dot2-based bigram.
// ---------------------------------------------------------------------------
__global__ __launch_bounds__(256) void mfma_proj2(
    const ushort_t* __restrict__ inBF2, const ushort_t* __restrict__ WcatT2,
    const float* __restrict__ bl,
    const float* __restrict__ bs1, const float* __restrict__ Ws2,
    const float* __restrict__ be1, const float* __restrict__ We2,
    ushort_t* __restrict__ leftH, ushort_t* __restrict__ rightH,
    float* __restrict__ parts)
{
    const int mt = blockIdx.x, ny = blockIdx.y;
    const int row0 = mt * 64;
    const int t = threadIdx.x, w = t >> 6, l = t & 63;
    const int wm = w >> 1, wn = w & 1;
    const int fr = l & 15, fg = l >> 4;

    __shared__ ushort_t As2[2][4096];
    __shared__ ushort_t Bs2[2][4096];
    __shared__ float red[2][64];

    const ushort_t* Abase = inBF2  + (size_t)mt * 8 * 4096;
    const ushort_t* Bbase = WcatT2 + (size_t)ny * 8 * 4096;

    f32x4 acc[2][2];
    #pragma unroll
    for (int m = 0; m < 2; ++m)
        #pragma unroll
        for (int n = 0; n < 2; ++n)
            acc[m][n] = f32x4{0.f, 0.f, 0.f, 0.f};

    const int c0 = 2 * w, c1 = 2 * w + 1;

#define STAGE(BI, KS)                                                        \
    {                                                                        \
        const ushort_t* ga = Abase + (KS) * 4096;                            \
        const ushort_t* gb = Bbase + (KS) * 4096;                            \
        gload_lds16(ga + c0 * 512 + l * 8, &As2[BI][c0 * 512]);              \
        gload_lds16(ga + c1 * 512 + l * 8, &As2[BI][c1 * 512]);              \
        gload_lds16(gb + c0 * 512 + l * 8, &Bs2[BI][c0 * 512]);              \
        gload_lds16(gb + c1 * 512 + l * 8, &Bs2[BI][c1 * 512]);              \
    }

    STAGE(0, 0);
    __syncthreads();

    for (int ks = 0; ks < 8; ++ks) {
        const int bi = ks & 1;
        if (ks < 7) STAGE(bi ^ 1, ks + 1);
        #pragma unroll
        for (int kk = 0; kk < 2; ++kk) {
            const int kc = kk * 4 + fg;
            bf16x8 a0 = *(const bf16x8*)&As2[bi][(kc * 64 + wm * 32 + fr) * 8];
            bf16x8 a1 = *(const bf16x8*)&As2[bi][(kc * 64 + wm * 32 + 16 + fr) * 8];
            bf16x8 b0 = *(const bf16x8*)&Bs2[bi][(kc * 64 + wn * 32 + fr) * 8];
            bf16x8 b1 = *(const bf16x8*)&Bs2[bi][(kc * 64 + wn * 32 + 16 + fr) * 8];
            acc[0][0] = __builtin_amdgcn_mfma_f32_16x16x32_bf16(a0, b0, acc[0][0], 0, 0, 0);
            acc[0][1] = __builtin_amdgcn_mfma_f32_16x16x32_bf16(a0, b1, acc[0][1], 0, 0, 0);
            acc[1][0] = __builtin_amdgcn_mfma_f32_16x16x32_bf16(a1, b0, acc[1][0], 0, 0, 0);
            acc[1][1] = __builtin_amdgcn_mfma_f32_16x16x32_bf16(a1, b1, acc[1][1], 0, 0, 0);
        }
        __syncthreads();
    }
#undef STAGE

    const int fq4 = fg << 2;
    if (ny < 4) {
        ushort_t* outp = (ny < 2) ? leftH : rightH;
        const int cbase = (ny & 1) * 64 + wn * 32;
        #pragma unroll
        for (int m = 0; m < 2; ++m) {
            const int row = row0 + wm * 32 + m * 16 + fq4;
            #pragma unroll
            for (int n = 0; n < 2; ++n) {
                const int col = cbase + n * 16 + fr;
                const float bv = (ny < 2) ? bl[col] : 0.f;
                #pragma unroll
                for (int q = 0; q < 4; ++q) {
                    float v = acc[m][n][q] + bv;
                    outp[(size_t)(row + q) * Pc + col] =
                        __builtin_bit_cast(ushort_t, (_Float16)v);
                }
            }
        }
    } else {
        const float* b1 = (ny < 6) ? bs1 : be1;
        const float* W2 = (ny < 6) ? Ws2 : We2;
        const int pbase = (ny < 6) ? (ny - 4) * 64 : (ny - 6) * 64;
        float vs[2][4];
        #pragma unroll
        for (int m = 0; m < 2; ++m)
            #pragma unroll
            for (int q = 0; q < 4; ++q) {
                float v = 0.f;
                #pragma unroll
                for (int n = 0; n < 2; ++n) {
                    const int cp = pbase + wn * 32 + n * 16 + fr;
                    v += fmaxf(acc[m][n][q] + b1[cp], 0.f) * W2[cp];
                }
                v += __shfl_xor(v, 1);
                v += __shfl_xor(v, 2);
                v += __shfl_xor(v, 4);
                v += __shfl_xor(v, 8);
                vs[m][q] = v;
            }
        if (fr == 0) {
            #pragma unroll
            for (int m = 0; m < 2; ++m)
                #pragma unroll
                for (int q = 0; q < 4; ++q)
                    red[wn][wm * 32 + m * 16 + fq4 + q] = vs[m][q];
        }
        __syncthreads();
        if (t < 64) {
            const int pi = ny - 4;
            parts[pi * ROWS + row0 + t] = red[0][t] + red[1][t];
        }
    }
}

// ---------------------------------------------------------------------------
// bigram v3: v1 shape (64i x 32j tile, thread = 4i x 2j), packed-f16 inner:
//   per 2 p's: v_pk_add_f16 + v_pk_max_f16 + v_dot2_f32_f16 (fp32 accum).
// grid (17, 8, 4): jt<16 compute; jt==16 combines start/end partials.
// ---------------------------------------------------------------------------
__global__ __launch_bounds__(256) void bigram_kernel(
    const ushort_t* __restrict__ leftH, const ushort_t* __restrict__ rightH,
    const float* __restrict__ Wo,   const float* __restrict__ bo,
    const float* __restrict__ parts,
    const float* __restrict__ bs2,  const float* __restrict__ be2,
    float* __restrict__ out, float* __restrict__ start_out,
    float* __restrict__ end_out)
{
    const int jt = blockIdx.x, it = blockIdx.y, b = blockIdx.z;
    const int t  = threadIdx.x;

    if (jt == 16) {
        const int base = (b * 8 + it) * 64;
        if (t < 64) {
            const int r = base + t;
            start_out[r] = parts[r] + parts[ROWS + r] + bs2[0];
        } else if (t < 128) {
            const int r = base + t - 64;
            end_out[r] = parts[2 * ROWS + r] + parts[3 * ROWS + r] + be2[0];
        }
        return;
    }

    __shared__ unsigned Lh[32][68];   // j rows, 64 f16-pairs + pad
    __shared__ unsigned Rh[64][68];   // i rows
    __shared__ unsigned woh[64];

    const ushort_t* lp = leftH  + (size_t)(b * Nc + jt * 32) * Pc;
    const ushort_t* rp = rightH + (size_t)(b * Nc + it * 64) * Pc;

    // stage L: 32 rows x 256B = 512 x 16B
    #pragma unroll
    for (int u = 0; u < 2; ++u) {
        int f = t + u * 256, r = f >> 4, c = f & 15;
        *(float4*)&Lh[r][c * 4] = *(const float4*)(lp + (size_t)r * Pc + c * 8);
    }
    // stage R: 64 rows x 256B = 1024 x 16B
    #pragma unroll
    for (int u = 0; u < 4; ++u) {
        int f = t + u * 256, r = f >> 4, c = f & 15;
        *(float4*)&Rh[r][c * 4] = *(const float4*)(rp + (size_t)r * Pc + c * 8);
    }
    if (t < 64) woh[t] = packh2(Wo[2 * t], Wo[2 * t + 1]);
    __syncthreads();

    const int jl = t & 15;   // j = jl + 16*jj, jj<2
    const int il = t >> 4;   // i = il + 16*ii, ii<4

    float acc[4][2] = {};
    const h2v hz = {(_Float16)0.f, (_Float16)0.f};

    #pragma unroll 8
    for (int s = 0; s < 32; ++s) {        // 4 p's per step
        uint2 w2 = *(const uint2*)&woh[2 * s];
        uint2 l2[2], r2[4];
        #pragma unroll
        for (int jj = 0; jj < 2; ++jj) l2[jj] = *(const uint2*)&Lh[jl + 16 * jj][2 * s];
        #pragma unroll
        for (int ii = 0; ii < 4; ++ii) r2[ii] = *(const uint2*)&Rh[il + 16 * ii][2 * s];

        #pragma unroll
        for (int h = 0; h < 2; ++h) {
            const unsigned wu = h ? w2.y : w2.x;
            h2v lv[2], rv[4];
            #pragma unroll
            for (int jj = 0; jj < 2; ++jj)
                lv[jj] = __builtin_bit_cast(h2v, h ? l2[jj].y : l2[jj].x);
            #pragma unroll
            for (int ii = 0; ii < 4; ++ii)
                rv[ii] = __builtin_bit_cast(h2v, h ? r2[ii].y : r2[ii].x);
            #pragma unroll
            for (int ii = 0; ii < 4; ++ii) {
                #pragma unroll
                for (int jj = 0; jj < 2; ++jj) {
                    h2v sum = lv[jj] + rv[ii];                       // v_pk_add_f16
                    sum = __builtin_elementwise_max(sum, hz);        // v_pk_max_f16
                    unsigned su = __builtin_bit_cast(unsigned, sum);
                    asm("v_dot2_f32_f16 %0, %1, %2, %0"
                        : "+v"(acc[ii][jj]) : "v"(su), "v"(wu));
                }
            }
        }
    }

    const float bias = bo[0];
    #pragma unroll
    for (int ii = 0; ii < 4; ++ii) {
        #pragma unroll
        for (int jj = 0; jj < 2; ++jj) {
            const int gi = it * 64 + il + 16 * ii;
            const int gj = jt * 32 + jl + 16 * jj;
            out[((size_t)b * Nc + gi) * Nc + gj] = acc[ii][jj] + bias;
        }
    }
}

extern "C" void kernel_launch(void* const* d_in, const int* in_sizes, int n_in,
                              void* d_out, int out_size, void* d_ws, size_t ws_size,
                              hipStream_t stream) {
    const float* input = (const float*)d_in[0];
    const float* Wl  = (const float*)d_in[1];
    const float* bl  = (const float*)d_in[2];
    const float* Wr  = (const float*)d_in[3];
    const float* Wo  = (const float*)d_in[4];
    const float* bo  = (const float*)d_in[5];
    const float* Ws1 = (const float*)d_in[6];
    const float* bs1 = (const float*)d_in[7];
    const float* Ws2 = (const float*)d_in[8];
    const float* bs2 = (const float*)d_in[9];
    const float* We1 = (const float*)d_in[10];
    const float* be1 = (const float*)d_in[11];
    const float* We2 = (const float*)d_in[12];
    const float* be2 = (const float*)d_in[13];

    float* out    = (float*)d_out;
    float* bigram = out;
    float* start  = out + (size_t)Bc * Nc * Nc;
    float* end    = start + (size_t)Bc * Nc;

    ushort_t* leftH  = (ushort_t*)d_ws;                  // 2048*128 f16
    ushort_t* rightH = leftH + (size_t)ROWS * Pc;        // 2048*128 f16
    float* parts     = (float*)(rightH + (size_t)ROWS * Pc);   // 4*2048 f32
    ushort_t* inBF2  = (ushort_t*)(parts + 4 * ROWS);    // 2048*512 bf16 (tiled)
    ushort_t* WcatT2 = inBF2 + (size_t)ROWS * Dc;        // 512*512 bf16 (tiled)

    convert_kernel<<<320, 256, 0, stream>>>(input, Wl, Wr, Ws1, We1, inBF2, WcatT2);

    mfma_proj2<<<dim3(32, 8), 256, 0, stream>>>(
        inBF2, WcatT2, bl, bs1, Ws2, be1, We2, leftH, rightH, parts);

    bigram_kernel<<<dim3(17, 8, 4), 256, 0, stream>>>(
        leftH, rightH, Wo, bo, parts, bs2, be2, bigram, start, end);
}